// Round 1
// baseline (425.979 us; speedup 1.0000x reference)
//
#include <hip/hip_runtime.h>
#include <cstdint>
#include <cstddef>

#define NEG_SLOPE 0.2f
#define LOG2E 1.44269504f

typedef __attribute__((ext_vector_type(8))) short short8;   // 8 bf16 (4 VGPRs)
typedef __attribute__((ext_vector_type(4))) float f32x4;    // MFMA accumulator
typedef __attribute__((ext_vector_type(2))) float f32x2;    // packed-f32 pair

__device__ __forceinline__ float bf2f(unsigned short u) {
    union { unsigned int i; float f; } x; x.i = ((unsigned int)u) << 16; return x.f;
}
__device__ __forceinline__ unsigned short f2bf(float f) {
    union { float f; unsigned int i; } x;
    x.f = f;
    unsigned int u = x.i;
    return (unsigned short)((u + 0x7FFFu + ((u >> 16) & 1u)) >> 16);   // RNE
}
// 2 bf16 (one dword, lo=even ch, hi=odd ch) -> 2 f32
__device__ __forceinline__ f32x2 cvt2(unsigned int u) {
    f32x2 r;
    r.x = __uint_as_float(u << 16);
    r.y = __uint_as_float(u & 0xFFFF0000u);
    return r;
}

// 4-lane (quad) sum via DPP on the VALU pipe: xor1, xor2 quad_perms.
// Requires the 4-lane group to be quad-aligned and uniformly active.
__device__ __forceinline__ float dpp_sum4(float p) {
    p += __int_as_float(__builtin_amdgcn_update_dpp(0, __float_as_int(p), 0xB1, 0xF, 0xF, true));  // quad_perm [1,0,3,2]
    p += __int_as_float(__builtin_amdgcn_update_dpp(0, __float_as_int(p), 0x4E, 0xF, 0xF, true));  // quad_perm [2,3,0,1]
    return p;
}

// =====================================================================
// Weight prep (all 3 layers in one launch) + zero the CSR count array
// (saves the hipMemsetAsync dispatch):
// Bt[n][k] = bf16([Wl | Wr][k][n]); layer0/1: dout=128, layer2: dout=32.
// =====================================================================
__global__ __launch_bounds__(256) void prep_w_all(
    const float* __restrict__ Wl0, const float* __restrict__ Wr0,
    const float* __restrict__ Wl1, const float* __restrict__ Wr1,
    const float* __restrict__ Wl2, const float* __restrict__ Wr2,
    unsigned short* __restrict__ Bt0, unsigned short* __restrict__ Bt1,
    unsigned short* __restrict__ Bt2, int* __restrict__ cnt, int N)
{
    int idx = blockIdx.x * 256 + threadIdx.x;
    for (int i = idx; i < N; i += gridDim.x * 256) cnt[i] = 0;
    const int SZ = 256 * 128;     // layer0/1 table elems
    const float *Wl, *Wr; unsigned short* Bt; int dout;
    if (idx < SZ)              { Wl = Wl0; Wr = Wr0; Bt = Bt0; dout = 128; }
    else if (idx < 2 * SZ)     { Wl = Wl1; Wr = Wr1; Bt = Bt1; dout = 128; idx -= SZ; }
    else if (idx < 2 * SZ + 64 * 128) { Wl = Wl2; Wr = Wr2; Bt = Bt2; dout = 32; idx -= 2 * SZ; }
    else return;
    int n = idx >> 7, k = idx & 127;
    float v = (n < dout) ? Wl[(size_t)k * dout + n] : Wr[(size_t)k * dout + (n - dout)];
    Bt[idx] = f2bf(v);
}

// =====================================================================
// MFMA GEMM (LDS-staged): XL(bf16) | XR(bf16) = A[M x 128] @ Bt^T + b.
// Block = 64 rows x BN cols, 256 threads (4 waves).
// =====================================================================
template<int BN, bool ABF16>
__global__ __launch_bounds__(256) void gemm_mfma(
    const void* __restrict__ Avoid, int M,
    const unsigned short* __restrict__ Bt,
    const float* __restrict__ bl, const float* __restrict__ br,
    int dout, unsigned short* __restrict__ XL, unsigned short* __restrict__ XR)
{
    constexpr int LDA = 136;                       // shorts; pad 128+8
    constexpr int NT  = BN / 16;
    __shared__ __attribute__((aligned(16))) unsigned short As[64 * LDA];
    __shared__ __attribute__((aligned(16))) unsigned short Bs[BN * LDA];
    const int t  = threadIdx.x;
    const int m0 = blockIdx.x * 64;
    const int n0 = blockIdx.y * BN;

    // ---- stage A (64 x 128 -> bf16 LDS), coalesced
    if (ABF16) {
        const unsigned short* A = (const unsigned short*)Avoid;
#pragma unroll
        for (int i = 0; i < 8; ++i) {
            int c   = t + i * 256;         // ushort4 chunks, [0, 2048)
            int row = c >> 5;              // 32 chunks per row
            int col = (c & 31) * 4;
            int gr  = m0 + row;
            ushort4 v = make_ushort4(0, 0, 0, 0);
            if (gr < M) v = *(const ushort4*)(A + (size_t)gr * 128 + col);
            *(ushort4*)(As + row * LDA + col) = v;
        }
    } else {
        const float* A = (const float*)Avoid;
#pragma unroll
        for (int i = 0; i < 8; ++i) {
            int c   = t + i * 256;         // float4 chunks, [0, 2048)
            int row = c >> 5;
            int col = (c & 31) * 4;
            int gr  = m0 + row;
            float4 v = make_float4(0.f, 0.f, 0.f, 0.f);
            if (gr < M) v = *(const float4*)(A + (size_t)gr * 128 + col);
            ushort4 o;
            o.x = f2bf(v.x); o.y = f2bf(v.y); o.z = f2bf(v.z); o.w = f2bf(v.w);
            *(ushort4*)(As + row * LDA + col) = o;
        }
    }
    // ---- stage B (BN x 128 bf16), coalesced
#pragma unroll
    for (int i = 0; i < BN / 16; ++i) {
        int c  = t + i * 256;              // short8 chunks
        int n  = c >> 4;                   // 16 chunks per row
        int kc = (c & 15) * 8;
        *(short8*)(Bs + n * LDA + kc) =
            *(const short8*)(Bt + (size_t)(n0 + n) * 128 + kc);
    }
    __syncthreads();

    const int w    = t >> 6;
    const int lane = t & 63;
    const int fr   = lane & 15;
    const int quad = lane >> 4;

    f32x4 acc[NT] = {};
    const unsigned short* ap = As + (w * 16 + fr) * LDA + quad * 8;
    const unsigned short* bp = Bs + fr * LDA + quad * 8;
#pragma unroll
    for (int k0 = 0; k0 < 128; k0 += 32) {
        short8 afr = *(const short8*)(ap + k0);
#pragma unroll
        for (int j = 0; j < NT; ++j) {
            short8 bfr = *(const short8*)(bp + j * 16 * LDA + k0);
            acc[j] = __builtin_amdgcn_mfma_f32_16x16x32_bf16(afr, bfr, acc[j], 0, 0, 0);
        }
    }

    // ---- epilogue: +bias, bf16 stores into XL | XR
#pragma unroll
    for (int j = 0; j < NT; ++j) {
        int col = n0 + j * 16 + fr;
        float bias = (col < dout) ? bl[col] : br[col - dout];
#pragma unroll
        for (int r = 0; r < 4; ++r) {
            int row = m0 + w * 16 + quad * 4 + r;
            if (row < M) {
                unsigned short o = f2bf(acc[j][r] + bias);
                if (col < dout) XL[(size_t)row * dout + col] = o;
                else            XR[(size_t)row * dout + (col - dout)] = o;
            }
        }
    }
}

// =====================================================================
// CSR build over dst: count+rank -> 3-phase device scan -> place.
// =====================================================================
__global__ void count_rank_kernel(const int* __restrict__ dst, int E,
                                  int* __restrict__ cnt, unsigned short* __restrict__ rank)
{
    int e = blockIdx.x * blockDim.x + threadIdx.x;
    if (e < E) {
        int p = atomicAdd(&cnt[dst[e]], 1);
        rank[e] = (unsigned short)p;
    }
}

__global__ __launch_bounds__(256) void scan_partial(
    const int* __restrict__ cnt, int N, int* __restrict__ bsum)
{
    __shared__ int red[4];
    const int t = threadIdx.x;
    const int base = blockIdx.x * 2048;
    int s = 0;
#pragma unroll
    for (int i = 0; i < 8; ++i) {
        int idx = base + t + i * 256;
        if (idx < N) s += cnt[idx];
    }
#pragma unroll
    for (int off = 32; off >= 1; off >>= 1) s += __shfl_xor(s, off);
    if ((t & 63) == 0) red[t >> 6] = s;
    __syncthreads();
    if (t == 0) bsum[blockIdx.x] = red[0] + red[1] + red[2] + red[3];
}

__global__ __launch_bounds__(256) void scan_bsums(
    int* __restrict__ bsum, int nb, int E, int* __restrict__ rowptr, int N)
{
    __shared__ int sh[256];
    const int t = threadIdx.x;
    int v = (t < nb) ? bsum[t] : 0;
    sh[t] = v;
    __syncthreads();
    for (int off = 1; off < 256; off <<= 1) {
        int u = (t >= off) ? sh[t - off] : 0;
        __syncthreads();
        sh[t] += u;
        __syncthreads();
    }
    if (t < nb) bsum[t] = sh[t] - v;   // exclusive prefix
    if (t == 0) rowptr[N] = E;
}

__global__ __launch_bounds__(256) void scan_final(
    const int* __restrict__ cnt, int N, const int* __restrict__ bsum,
    int* __restrict__ rowptr)
{
    __shared__ int sdat[2048];
    __shared__ int tsum[256];
    const int t = threadIdx.x;
    const int base = blockIdx.x * 2048;
#pragma unroll
    for (int i = 0; i < 8; ++i) {
        int idx = base + t + i * 256;
        sdat[t + i * 256] = (idx < N) ? cnt[idx] : 0;
    }
    __syncthreads();
    int vals[8];
    int s = 0;
#pragma unroll
    for (int j = 0; j < 8; ++j) { vals[j] = sdat[t * 8 + j]; s += vals[j]; }
    tsum[t] = s;
    __syncthreads();
    for (int off = 1; off < 256; off <<= 1) {
        int u = (t >= off) ? tsum[t - off] : 0;
        __syncthreads();
        tsum[t] += u;
        __syncthreads();
    }
    int run = bsum[blockIdx.x] + tsum[t] - s;   // exclusive prefix of this chunk
#pragma unroll
    for (int j = 0; j < 8; ++j) { sdat[t * 8 + j] = run; run += vals[j]; }
    __syncthreads();
#pragma unroll
    for (int i = 0; i < 8; ++i) {
        int idx = base + t + i * 256;
        if (idx < N) rowptr[idx] = sdat[t + i * 256];
    }
}

__global__ void place_kernel(const int* __restrict__ src, const int* __restrict__ dst,
                             const unsigned short* __restrict__ rank, int E,
                             const int* __restrict__ rowptr,
                             unsigned short* __restrict__ csr_src)
{
    int e = blockIdx.x * blockDim.x + threadIdx.x;
    if (e < E)
        csr_src[rowptr[dst[e]] + rank[e]] = (unsigned short)src[e];
}

// =====================================================================
// Fused GATv2 edge phase — 8 ch/lane (16B gather loads), leaky-relu
// folded into the logit dot via leaky(s)=0.6s+0.4|s| (|s| is a free
// VOP3 modifier): per channel the old {add,mul,max,fma} becomes
// {pk_add/2, fma, fma}. Head reduce is a 2-op DPP quad sum. Packable
// elementwise work uses float2 (v_pk_add_f32/v_pk_fma_f32).
// =====================================================================
template<int H>
__global__ __launch_bounds__(256, 4) void gat_fused(
    const unsigned short* __restrict__ xl, const unsigned short* __restrict__ xr,
    const int* __restrict__ rowptr, const unsigned short* __restrict__ csr_src,
    const float* __restrict__ att, const float* __restrict__ bias,
    unsigned short* __restrict__ hout, int hstride, int N)
{
    constexpr int HC  = 32 * H;
    constexpr int LPE = HC / 8;      // lanes per edge, 8 ch each (H=4: 16, H=1: 4)
    constexpr int EPW = 64 / LPE;    // edge slots per wave (4 / 16)
    const int node = blockIdx.x * 4 + (threadIdx.x >> 6);
    if (node >= N) return;
    const int lane = threadIdx.x & 63;
    const int q    = lane % LPE;     // channel group: ch [8q, 8q+8)
    const int slot = lane / LPE;
    const int rs   = rowptr[node];
    const int re   = rowptr[node + 1];

    const unsigned short* __restrict__ xlb = xl + 8 * q;

    // xr_i for this node's 8 channels
    f32x2 xri[4];
    {
        uint4 u = *(const uint4*)(xr + (size_t)node * HC + 8 * q);
        xri[0] = cvt2(u.x); xri[1] = cvt2(u.y); xri[2] = cvt2(u.z); xri[3] = cvt2(u.w);
    }
    // logit coefs: att * leaky folded, in exp2 domain
    float b1[8], b2[8];
    {
        const float4 a0 = *(const float4*)(att + 8 * q);
        const float4 a1 = *(const float4*)(att + 8 * q + 4);
        const float c1 = 0.5f * (1.0f + NEG_SLOPE) * LOG2E;   // 0.6*log2e
        const float c2 = 0.5f * (1.0f - NEG_SLOPE) * LOG2E;   // 0.4*log2e
        b1[0] = a0.x * c1; b1[1] = a0.y * c1; b1[2] = a0.z * c1; b1[3] = a0.w * c1;
        b1[4] = a1.x * c1; b1[5] = a1.y * c1; b1[6] = a1.z * c1; b1[7] = a1.w * c1;
        b2[0] = a0.x * c2; b2[1] = a0.y * c2; b2[2] = a0.z * c2; b2[3] = a0.w * c2;
        b2[4] = a1.x * c2; b2[5] = a1.y * c2; b2[6] = a1.z * c2; b2[7] = a1.w * c2;
    }

    float l = 0.f;
    f32x2 acc[4] = {};

    // edge weight + xl row (8 ch) for source s
    auto edge = [&](int s, f32x2* v) -> float {
        uint4 u = *(const uint4*)(xlb + (unsigned)s * HC);
        v[0] = cvt2(u.x); v[1] = cvt2(u.y); v[2] = cvt2(u.z); v[3] = cvt2(u.w);
        float p = 0.f, pq = 0.f;
#pragma unroll
        for (int i = 0; i < 4; ++i) {
            f32x2 sv = v[i] + xri[i];                         // v_pk_add_f32
            p  = fmaf(b1[2 * i],     sv.x, p);
            pq = fmaf(b2[2 * i],     fabsf(sv.x), pq);        // abs = free modifier
            p  = fmaf(b1[2 * i + 1], sv.y, p);
            pq = fmaf(b2[2 * i + 1], fabsf(sv.y), pq);
        }
        p += pq;
        p = dpp_sum4(p);              // 32ch head = 4 lanes: quad reduce, VALU pipe
        return exp2f(p);
    };

    // ---- self-loop (src = dst = node), slot 0 only
    if (slot == 0) {
        f32x2 v[4];
        float w = edge(node, v);
        l = w;
        f32x2 w2 = {w, w};
#pragma unroll
        for (int i = 0; i < 4; ++i) acc[i] = w2 * v[i];
    }

    // ---- incoming edges, strided per slot, unrolled x2
    int k = rs + slot;
    for (; k + EPW < re; k += 2 * EPW) {
        int s0 = csr_src[k];
        int s1 = csr_src[k + EPW];
        f32x2 v0[4], v1[4];
        float w0 = edge(s0, v0);
        float w1 = edge(s1, v1);
        l += w0 + w1;
        f32x2 w02 = {w0, w0}, w12 = {w1, w1};
#pragma unroll
        for (int i = 0; i < 4; ++i)
            acc[i] += w02 * v0[i] + w12 * v1[i];              // 2x v_pk_fma_f32
    }
    if (k < re) {
        int s0 = csr_src[k];
        f32x2 v0[4];
        float w0 = edge(s0, v0);
        l += w0;
        f32x2 w02 = {w0, w0};
#pragma unroll
        for (int i = 0; i < 4; ++i) acc[i] += w02 * v0[i];
    }

    // ---- merge edge slots (once per node)
#pragma unroll
    for (int mask = LPE; mask < 64; mask <<= 1) {
        l += __shfl_xor(l, mask);
#pragma unroll
        for (int i = 0; i < 4; ++i) {
            acc[i].x += __shfl_xor(acc[i].x, mask);
            acc[i].y += __shfl_xor(acc[i].y, mask);
        }
    }

    if (lane < LPE) {
        const float4 bi0 = *(const float4*)(bias + 8 * q);
        const float4 bi1 = *(const float4*)(bias + 8 * q + 4);
        float inv = 1.f / (l + 1e-16f);
        float o[8];
        o[0] = acc[0].x * inv + bi0.x; o[1] = acc[0].y * inv + bi0.y;
        o[2] = acc[1].x * inv + bi0.z; o[3] = acc[1].y * inv + bi0.w;
        o[4] = acc[2].x * inv + bi1.x; o[5] = acc[2].y * inv + bi1.y;
        o[6] = acc[3].x * inv + bi1.z; o[7] = acc[3].y * inv + bi1.w;
#pragma unroll
        for (int i = 0; i < 8; ++i)
            o[i] = (o[i] > 0.f) ? o[i] : expm1f(o[i]);        // ELU
        uint4 ob;
        ob.x = ((unsigned)f2bf(o[1]) << 16) | f2bf(o[0]);
        ob.y = ((unsigned)f2bf(o[3]) << 16) | f2bf(o[2]);
        ob.z = ((unsigned)f2bf(o[5]) << 16) | f2bf(o[4]);
        ob.w = ((unsigned)f2bf(o[7]) << 16) | f2bf(o[6]);
        *(uint4*)(hout + (size_t)node * hstride + 8 * q) = ob;
    }
}

// =====================================================================
// Fused mean-pool + MLP head (h is bf16). One block per graph; batch is
// SORTED so graph b's nodes are rows [lower_bound(b), lower_bound(b+1)).
// =====================================================================
__global__ __launch_bounds__(128) void pool_head_kernel(
    const unsigned short* __restrict__ h, int hstride,
    const int* __restrict__ batch, int N,
    const float* __restrict__ meta,
    const float* __restrict__ Wh1, const float* __restrict__ bh1,
    const float* __restrict__ Wh2, const float* __restrict__ bh2,
    float* __restrict__ out)
{
    const int b = blockIdx.x;
    const int t = threadIdx.x;
    __shared__ float s[128];
    __shared__ float z[44];

    int lo = 0, hi = N;
    while (lo < hi) { int mid = (lo + hi) >> 1; if (batch[mid] < b) lo = mid + 1; else hi = mid; }
    int lo2 = lo, hi2 = N;
    while (lo2 < hi2) { int mid = (lo2 + hi2) >> 1; if (batch[mid] < b + 1) lo2 = mid + 1; else hi2 = mid; }
    const int start = lo, end = lo2;

    const int c = t & 31, r = t >> 5;     // 4 rows x 32 channels in flight
    float acc = 0.f;
    for (int row = start + r; row < end; row += 4)
        acc += bf2f(h[(size_t)row * hstride + c]);
    s[t] = acc;
    __syncthreads();
    if (t < 32) {
        float sum = s[t] + s[t + 32] + s[t + 64] + s[t + 96];
        z[t] = sum / fmaxf((float)(end - start), 1.0f);
    } else if (t < 44) {
        z[t] = meta[(size_t)b * 12 + (t - 32)];
    }
    __syncthreads();
    if (t < 32) {
        float hj = bh1[t];
#pragma unroll
        for (int k = 0; k < 44; ++k)
            hj = fmaf(z[k], Wh1[k * 32 + t], hj);
        hj = fmaxf(hj, 0.f);
        float p = hj * Wh2[t];
#pragma unroll
        for (int off = 16; off >= 1; off >>= 1)
            p += __shfl_xor(p, off, 32);
        if (t == 0) out[b] = p + bh2[0];
    }
}

// =====================================================================
extern "C" void kernel_launch(void* const* d_in, const int* in_sizes, int n_in,
                              void* d_out, int out_size, void* d_ws, size_t ws_size,
                              hipStream_t stream)
{
    const float* x     = (const float*)d_in[0];
    const int*   ei    = (const int*)d_in[1];
    const int*   batch = (const int*)d_in[2];
    const float* meta  = (const float*)d_in[3];
    const float* Wl[3]  = {(const float*)d_in[4],  (const float*)d_in[10], (const float*)d_in[16]};
    const float* bl[3]  = {(const float*)d_in[5],  (const float*)d_in[11], (const float*)d_in[17]};
    const float* Wr[3]  = {(const float*)d_in[6],  (const float*)d_in[12], (const float*)d_in[18]};
    const float* br[3]  = {(const float*)d_in[7],  (const float*)d_in[13], (const float*)d_in[19]};
    const float* att[3] = {(const float*)d_in[8],  (const float*)d_in[14], (const float*)d_in[20]};
    const float* bb[3]  = {(const float*)d_in[9],  (const float*)d_in[15], (const float*)d_in[21]};
    const float* Wh1 = (const float*)d_in[22];
    const float* bh1 = (const float*)d_in[23];
    const float* Wh2 = (const float*)d_in[24];
    const float* bh2 = (const float*)d_in[25];
    float* out = (float*)d_out;

    const int N  = in_sizes[0] / 128;
    const int E  = in_sizes[1] / 2;
    const int B  = in_sizes[3] / 12;
    const int NB = (N + 2047) / 2048;   // scan tiles (<= 256)

    char* wsp = (char*)d_ws;
    size_t off_ = 0;
    auto alloc = [&](size_t bytes) {
        char* p = wsp + off_;
        off_ = (off_ + bytes + 255) & ~(size_t)255;
        return p;
    };
    unsigned short* xlbuf = (unsigned short*)alloc((size_t)N * 128 * 2);  // bf16 gather table
    unsigned short* xrbuf = (unsigned short*)alloc((size_t)N * 128 * 2);  // bf16 xr table
    unsigned short* hbuf  = (unsigned short*)alloc((size_t)N * 128 * 2);  // bf16 layer output
    int*   cnt     = (int*)alloc((size_t)N * 4);
    int*   rowptr  = (int*)alloc((size_t)(N + 1) * 4);
    unsigned short* rank    = (unsigned short*)alloc((size_t)E * 2);  // rank within dst bucket
    unsigned short* csr_src = (unsigned short*)alloc((size_t)E * 2);  // src < 65536
    unsigned short* Bt0     = (unsigned short*)alloc((size_t)256 * 128 * 2);
    unsigned short* Bt1     = (unsigned short*)alloc((size_t)256 * 128 * 2);
    unsigned short* Bt2     = (unsigned short*)alloc((size_t)64 * 128 * 2);
    int*   bsum    = (int*)alloc((size_t)256 * 4);

    const int* srcI = ei;
    const int* dstI = ei + E;

    // ---- weight prep + cnt zeroing (one launch, no memset dispatch)
    prep_w_all<<<(2 * 256 * 128 + 64 * 128 + 255) / 256, 256, 0, stream>>>(
        Wl[0], Wr[0], Wl[1], Wr[1], Wl[2], Wr[2], Bt0, Bt1, Bt2, cnt, N);

    // ---- CSR over dst (real edges; self-loops handled inside gat_fused)
    count_rank_kernel<<<(E + 255) / 256, 256, 0, stream>>>(dstI, E, cnt, rank);
    scan_partial<<<NB, 256, 0, stream>>>(cnt, N, bsum);
    scan_bsums<<<1, 256, 0, stream>>>(bsum, NB, E, rowptr, N);
    scan_final<<<NB, 256, 0, stream>>>(cnt, N, bsum, rowptr);
    place_kernel<<<(E + 255) / 256, 256, 0, stream>>>(srcI, dstI, rank, E, rowptr, csr_src);

    const int GB = (N + 3) / 4;     // gat_fused blocks (4 nodes / 256-thread block)
    const int MB = (N + 63) / 64;   // gemm row-tiles (BM=64)

    // ---- layer 0 (din=128 f32, H=4, C=32, concat)
    {
        gemm_mfma<128, false><<<dim3(MB, 2), 256, 0, stream>>>(x, N, Bt0, bl[0], br[0], 128, xlbuf, xrbuf);
        gat_fused<4><<<GB, 256, 0, stream>>>(xlbuf, xrbuf, rowptr, csr_src, att[0], bb[0], hbuf, 128, N);
    }
    // ---- layer 1 (din=128 bf16)
    {
        gemm_mfma<128, true><<<dim3(MB, 2), 256, 0, stream>>>(hbuf, N, Bt1, bl[1], br[1], 128, xlbuf, xrbuf);
        gat_fused<4><<<GB, 256, 0, stream>>>(xlbuf, xrbuf, rowptr, csr_src, att[1], bb[1], hbuf, 128, N);
    }
    // ---- layer 2 (H=1, concat=False -> mean over 1 head = identity)
    {
        gemm_mfma<64, true><<<dim3(MB, 1), 256, 0, stream>>>(hbuf, N, Bt2, bl[2], br[2], 32, xlbuf, xrbuf);
        gat_fused<1><<<GB, 256, 0, stream>>>(xlbuf, xrbuf, rowptr, csr_src, att[2], bb[2], hbuf, 32, N);
    }
    // ---- fused global mean pool + head (batch sorted -> binary search, no atomics)
    pool_head_kernel<<<B, 128, 0, stream>>>(hbuf, 32, batch, N, meta, Wh1, bh1, Wh2, bh2, out);
}

// Round 2
// 377.284 us; speedup vs baseline: 1.1291x; 1.1291x over previous
//
#include <hip/hip_runtime.h>
#include <cstdint>
#include <cstddef>

#define NEG_SLOPE 0.2f
#define LOG2E 1.44269504f

typedef __attribute__((ext_vector_type(8))) short short8;   // 8 bf16 (4 VGPRs)
typedef __attribute__((ext_vector_type(4))) float f32x4;    // MFMA accumulator

__device__ __forceinline__ float bf2f(unsigned short u) {
    union { unsigned int i; float f; } x; x.i = ((unsigned int)u) << 16; return x.f;
}
__device__ __forceinline__ unsigned short f2bf(float f) {
    union { float f; unsigned int i; } x;
    x.f = f;
    unsigned int u = x.i;
    return (unsigned short)((u + 0x7FFFu + ((u >> 16) & 1u)) >> 16);   // RNE
}

// 8-lane sum via DPP (VALU pipe, no ds_bpermute): xor1, xor2 quad_perms,
// then row_half_mirror picks up the other quad's sum. Requires the 8-lane
// group to be lane-aligned to 8 and uniformly active (true here).
__device__ __forceinline__ float dpp_sum8(float p) {
    p += __int_as_float(__builtin_amdgcn_update_dpp(0, __float_as_int(p), 0xB1, 0xF, 0xF, true));  // quad_perm [1,0,3,2]
    p += __int_as_float(__builtin_amdgcn_update_dpp(0, __float_as_int(p), 0x4E, 0xF, 0xF, true));  // quad_perm [2,3,0,1]
    p += __int_as_float(__builtin_amdgcn_update_dpp(0, __float_as_int(p), 0x141, 0xF, 0xF, true)); // row_half_mirror
    return p;
}

// =====================================================================
// Weight prep (all 3 layers in one launch) + zero the CSR count array
// (saves the hipMemsetAsync dispatch):
// Bt[n][k] = bf16([Wl | Wr][k][n]); layer0/1: dout=128, layer2: dout=32.
// =====================================================================
__global__ __launch_bounds__(256) void prep_w_all(
    const float* __restrict__ Wl0, const float* __restrict__ Wr0,
    const float* __restrict__ Wl1, const float* __restrict__ Wr1,
    const float* __restrict__ Wl2, const float* __restrict__ Wr2,
    unsigned short* __restrict__ Bt0, unsigned short* __restrict__ Bt1,
    unsigned short* __restrict__ Bt2, int* __restrict__ cnt, int N)
{
    int idx = blockIdx.x * 256 + threadIdx.x;
    for (int i = idx; i < N; i += gridDim.x * 256) cnt[i] = 0;
    const int SZ = 256 * 128;     // layer0/1 table elems
    const float *Wl, *Wr; unsigned short* Bt; int dout;
    if (idx < SZ)              { Wl = Wl0; Wr = Wr0; Bt = Bt0; dout = 128; }
    else if (idx < 2 * SZ)     { Wl = Wl1; Wr = Wr1; Bt = Bt1; dout = 128; idx -= SZ; }
    else if (idx < 2 * SZ + 64 * 128) { Wl = Wl2; Wr = Wr2; Bt = Bt2; dout = 32; idx -= 2 * SZ; }
    else return;
    int n = idx >> 7, k = idx & 127;
    float v = (n < dout) ? Wl[(size_t)k * dout + n] : Wr[(size_t)k * dout + (n - dout)];
    Bt[idx] = f2bf(v);
}

// =====================================================================
// MFMA GEMM (LDS-staged): XL(bf16) | XR(bf16) = A[M x 128] @ Bt^T + b.
// Block = 64 rows x BN cols, 256 threads (4 waves).
// =====================================================================
template<int BN, bool ABF16>
__global__ __launch_bounds__(256) void gemm_mfma(
    const void* __restrict__ Avoid, int M,
    const unsigned short* __restrict__ Bt,
    const float* __restrict__ bl, const float* __restrict__ br,
    int dout, unsigned short* __restrict__ XL, unsigned short* __restrict__ XR)
{
    constexpr int LDA = 136;                       // shorts; pad 128+8
    constexpr int NT  = BN / 16;
    __shared__ __attribute__((aligned(16))) unsigned short As[64 * LDA];
    __shared__ __attribute__((aligned(16))) unsigned short Bs[BN * LDA];
    const int t  = threadIdx.x;
    const int m0 = blockIdx.x * 64;
    const int n0 = blockIdx.y * BN;

    // ---- stage A (64 x 128 -> bf16 LDS), coalesced
    if (ABF16) {
        const unsigned short* A = (const unsigned short*)Avoid;
#pragma unroll
        for (int i = 0; i < 8; ++i) {
            int c   = t + i * 256;         // ushort4 chunks, [0, 2048)
            int row = c >> 5;              // 32 chunks per row
            int col = (c & 31) * 4;
            int gr  = m0 + row;
            ushort4 v = make_ushort4(0, 0, 0, 0);
            if (gr < M) v = *(const ushort4*)(A + (size_t)gr * 128 + col);
            *(ushort4*)(As + row * LDA + col) = v;
        }
    } else {
        const float* A = (const float*)Avoid;
#pragma unroll
        for (int i = 0; i < 8; ++i) {
            int c   = t + i * 256;         // float4 chunks, [0, 2048)
            int row = c >> 5;
            int col = (c & 31) * 4;
            int gr  = m0 + row;
            float4 v = make_float4(0.f, 0.f, 0.f, 0.f);
            if (gr < M) v = *(const float4*)(A + (size_t)gr * 128 + col);
            ushort4 o;
            o.x = f2bf(v.x); o.y = f2bf(v.y); o.z = f2bf(v.z); o.w = f2bf(v.w);
            *(ushort4*)(As + row * LDA + col) = o;
        }
    }
    // ---- stage B (BN x 128 bf16), coalesced
#pragma unroll
    for (int i = 0; i < BN / 16; ++i) {
        int c  = t + i * 256;              // short8 chunks
        int n  = c >> 4;                   // 16 chunks per row
        int kc = (c & 15) * 8;
        *(short8*)(Bs + n * LDA + kc) =
            *(const short8*)(Bt + (size_t)(n0 + n) * 128 + kc);
    }
    __syncthreads();

    const int w    = t >> 6;
    const int lane = t & 63;
    const int fr   = lane & 15;
    const int quad = lane >> 4;

    f32x4 acc[NT] = {};
    const unsigned short* ap = As + (w * 16 + fr) * LDA + quad * 8;
    const unsigned short* bp = Bs + fr * LDA + quad * 8;
#pragma unroll
    for (int k0 = 0; k0 < 128; k0 += 32) {
        short8 afr = *(const short8*)(ap + k0);
#pragma unroll
        for (int j = 0; j < NT; ++j) {
            short8 bfr = *(const short8*)(bp + j * 16 * LDA + k0);
            acc[j] = __builtin_amdgcn_mfma_f32_16x16x32_bf16(afr, bfr, acc[j], 0, 0, 0);
        }
    }

    // ---- epilogue: +bias, bf16 stores into XL | XR
#pragma unroll
    for (int j = 0; j < NT; ++j) {
        int col = n0 + j * 16 + fr;
        float bias = (col < dout) ? bl[col] : br[col - dout];
#pragma unroll
        for (int r = 0; r < 4; ++r) {
            int row = m0 + w * 16 + quad * 4 + r;
            if (row < M) {
                unsigned short o = f2bf(acc[j][r] + bias);
                if (col < dout) XL[(size_t)row * dout + col] = o;
                else            XR[(size_t)row * dout + (col - dout)] = o;
            }
        }
    }
}

// =====================================================================
// CSR build over dst: count+rank -> 3-phase device scan -> place.
// =====================================================================
__global__ void count_rank_kernel(const int* __restrict__ dst, int E,
                                  int* __restrict__ cnt, unsigned short* __restrict__ rank)
{
    int e = blockIdx.x * blockDim.x + threadIdx.x;
    if (e < E) {
        int p = atomicAdd(&cnt[dst[e]], 1);
        rank[e] = (unsigned short)p;
    }
}

__global__ __launch_bounds__(256) void scan_partial(
    const int* __restrict__ cnt, int N, int* __restrict__ bsum)
{
    __shared__ int red[4];
    const int t = threadIdx.x;
    const int base = blockIdx.x * 2048;
    int s = 0;
#pragma unroll
    for (int i = 0; i < 8; ++i) {
        int idx = base + t + i * 256;
        if (idx < N) s += cnt[idx];
    }
#pragma unroll
    for (int off = 32; off >= 1; off >>= 1) s += __shfl_xor(s, off);
    if ((t & 63) == 0) red[t >> 6] = s;
    __syncthreads();
    if (t == 0) bsum[blockIdx.x] = red[0] + red[1] + red[2] + red[3];
}

__global__ __launch_bounds__(256) void scan_bsums(
    int* __restrict__ bsum, int nb, int E, int* __restrict__ rowptr, int N)
{
    __shared__ int sh[256];
    const int t = threadIdx.x;
    int v = (t < nb) ? bsum[t] : 0;
    sh[t] = v;
    __syncthreads();
    for (int off = 1; off < 256; off <<= 1) {
        int u = (t >= off) ? sh[t - off] : 0;
        __syncthreads();
        sh[t] += u;
        __syncthreads();
    }
    if (t < nb) bsum[t] = sh[t] - v;   // exclusive prefix
    if (t == 0) rowptr[N] = E;
}

__global__ __launch_bounds__(256) void scan_final(
    const int* __restrict__ cnt, int N, const int* __restrict__ bsum,
    int* __restrict__ rowptr)
{
    __shared__ int sdat[2048];
    __shared__ int tsum[256];
    const int t = threadIdx.x;
    const int base = blockIdx.x * 2048;
#pragma unroll
    for (int i = 0; i < 8; ++i) {
        int idx = base + t + i * 256;
        sdat[t + i * 256] = (idx < N) ? cnt[idx] : 0;
    }
    __syncthreads();
    int vals[8];
    int s = 0;
#pragma unroll
    for (int j = 0; j < 8; ++j) { vals[j] = sdat[t * 8 + j]; s += vals[j]; }
    tsum[t] = s;
    __syncthreads();
    for (int off = 1; off < 256; off <<= 1) {
        int u = (t >= off) ? tsum[t - off] : 0;
        __syncthreads();
        tsum[t] += u;
        __syncthreads();
    }
    int run = bsum[blockIdx.x] + tsum[t] - s;   // exclusive prefix of this chunk
#pragma unroll
    for (int j = 0; j < 8; ++j) { sdat[t * 8 + j] = run; run += vals[j]; }
    __syncthreads();
#pragma unroll
    for (int i = 0; i < 8; ++i) {
        int idx = base + t + i * 256;
        if (idx < N) rowptr[idx] = sdat[t + i * 256];
    }
}

__global__ void place_kernel(const int* __restrict__ src, const int* __restrict__ dst,
                             const unsigned short* __restrict__ rank, int E,
                             const int* __restrict__ rowptr,
                             unsigned short* __restrict__ csr_src)
{
    int e = blockIdx.x * blockDim.x + threadIdx.x;
    if (e < E)
        csr_src[rowptr[dst[e]] + rank[e]] = (unsigned short)src[e];
}

// =====================================================================
// Fused GATv2 edge phase — bf16 xl/xr tables, bf16 output, 4 ch/lane
// (r0-winner structure: straight-line scalar float4 math, dpp_sum8 head
// reduce on the VALU pipe, zero LDS-pipe ops in the hot loop).
// NEW vs r0: leaky-relu folded into the logit dot. leaky(s) for slope
// 0.2 is exactly 0.6s + 0.4|s|, so att.leaky(s)*log2e = sum b1*s + b2*|s|
// with b1=0.6*att*log2e, b2=0.4*att*log2e hoisted. Per channel the old
// {v_mul, v_max, v_fma} (3 ops) becomes {v_fma, v_fma(abs mod)} (2 ops;
// fabsf is a free VOP3 input modifier). Two accumulator chains keep the
// dependency depth at 4+1.
// =====================================================================
template<int H>
__global__ __launch_bounds__(256, 4) void gat_fused(
    const unsigned short* __restrict__ xl, const unsigned short* __restrict__ xr,
    const int* __restrict__ rowptr, const unsigned short* __restrict__ csr_src,
    const float* __restrict__ att, const float* __restrict__ bias,
    unsigned short* __restrict__ hout, int hstride, int N)
{
    constexpr int HC  = 32 * H;
    constexpr int LPE = HC / 4;      // lanes per edge (H=4: 32, H=1: 8)
    constexpr int EPW = 64 / LPE;    // edge slots per wave (2 / 8)
    const int node = blockIdx.x * 4 + (threadIdx.x >> 6);
    if (node >= N) return;
    const int lane = threadIdx.x & 63;
    const int q    = lane % LPE;
    const int slot = lane / LPE;
    const int rs   = rowptr[node];
    const int re   = rowptr[node + 1];

    const unsigned short* __restrict__ xlb = xl + 4 * q;
    float4 xri;
    {
        ushort4 u = *(const ushort4*)(xr + (size_t)node * HC + 4 * q);
        xri.x = bf2f(u.x); xri.y = bf2f(u.y); xri.z = bf2f(u.z); xri.w = bf2f(u.w);
    }
    // logit coefs with leaky folded, exp2 domain
    float4 b1, b2;
    {
        float4 a = *(const float4*)(att + 4 * q);
        const float c1 = 0.5f * (1.0f + NEG_SLOPE) * LOG2E;   // 0.6*log2e
        const float c2 = 0.5f * (1.0f - NEG_SLOPE) * LOG2E;   // 0.4*log2e
        b1.x = a.x * c1; b1.y = a.y * c1; b1.z = a.z * c1; b1.w = a.w * c1;
        b2.x = a.x * c2; b2.y = a.y * c2; b2.z = a.z * c2; b2.w = a.w * c2;
    }

    float l = 0.f;
    float4 acc = make_float4(0.f, 0.f, 0.f, 0.f);

    auto ld4 = [&](int s) -> float4 {
        ushort4 u = *(const ushort4*)(xlb + (size_t)s * HC);
        float4 v;
        v.x = bf2f(u.x); v.y = bf2f(u.y); v.z = bf2f(u.z); v.w = bf2f(u.w);
        return v;
    };

    auto edge_w = [&](const float4& v) -> float {   // exp2(att . leakyrelu(v+xri))
        float sx = v.x + xri.x, sy = v.y + xri.y, sz = v.z + xri.z, sw = v.w + xri.w;
        float p  = b1.x * sx;
        float pq = b2.x * fabsf(sx);
        p  = fmaf(b1.y, sy, p);
        pq = fmaf(b2.y, fabsf(sy), pq);
        p  = fmaf(b1.z, sz, p);
        pq = fmaf(b2.z, fabsf(sz), pq);
        p  = fmaf(b1.w, sw, p);
        pq = fmaf(b2.w, fabsf(sw), pq);
        p += pq;
        p = dpp_sum8(p);                 // 8-lane head reduce, VALU pipe
        return exp2f(p);
    };

    // ---- self-loop (src = dst = node), slot 0 only
    if (slot == 0) {
        float4 v = ld4(node);
        float w = edge_w(v);
        l = w;
        acc.x = w * v.x; acc.y = w * v.y; acc.z = w * v.z; acc.w = w * v.w;
    }

    // ---- incoming edges, strided per slot, unrolled x2 (no predication)
    int k = rs + slot;
    for (; k + EPW < re; k += 2 * EPW) {
        int s0 = csr_src[k];
        int s1 = csr_src[k + EPW];
        float4 v0 = ld4(s0);
        float4 v1 = ld4(s1);
        float w0 = edge_w(v0);
        float w1 = edge_w(v1);
        l += w0 + w1;
        acc.x = fmaf(w0, v0.x, fmaf(w1, v1.x, acc.x));
        acc.y = fmaf(w0, v0.y, fmaf(w1, v1.y, acc.y));
        acc.z = fmaf(w0, v0.z, fmaf(w1, v1.z, acc.z));
        acc.w = fmaf(w0, v0.w, fmaf(w1, v1.w, acc.w));
    }
    if (k < re) {
        int s0 = csr_src[k];
        float4 v0 = ld4(s0);
        float w0 = edge_w(v0);
        l += w0;
        acc.x = fmaf(w0, v0.x, acc.x);
        acc.y = fmaf(w0, v0.y, acc.y);
        acc.z = fmaf(w0, v0.z, acc.z);
        acc.w = fmaf(w0, v0.w, acc.w);
    }

    // ---- merge edge slots: plain sums (once per node)
#pragma unroll
    for (int mask = LPE; mask < 64; mask <<= 1) {
        l     += __shfl_xor(l, mask);
        acc.x += __shfl_xor(acc.x, mask);
        acc.y += __shfl_xor(acc.y, mask);
        acc.z += __shfl_xor(acc.z, mask);
        acc.w += __shfl_xor(acc.w, mask);
    }

    if (lane < LPE) {
        const float4 bi = *(const float4*)(bias + 4 * q);
        float inv = 1.f / (l + 1e-16f);
        float4 o;
        o.x = acc.x * inv + bi.x;
        o.y = acc.y * inv + bi.y;
        o.z = acc.z * inv + bi.z;
        o.w = acc.w * inv + bi.w;
        o.x = (o.x > 0.f) ? o.x : expm1f(o.x);
        o.y = (o.y > 0.f) ? o.y : expm1f(o.y);
        o.z = (o.z > 0.f) ? o.z : expm1f(o.z);
        o.w = (o.w > 0.f) ? o.w : expm1f(o.w);
        ushort4 ob;
        ob.x = f2bf(o.x); ob.y = f2bf(o.y); ob.z = f2bf(o.z); ob.w = f2bf(o.w);
        *(ushort4*)(hout + (size_t)node * hstride + 4 * q) = ob;
    }
}

// =====================================================================
// Fused mean-pool + MLP head (h is bf16). One block per graph; batch is
// SORTED so graph b's nodes are rows [lower_bound(b), lower_bound(b+1)).
// =====================================================================
__global__ __launch_bounds__(128) void pool_head_kernel(
    const unsigned short* __restrict__ h, int hstride,
    const int* __restrict__ batch, int N,
    const float* __restrict__ meta,
    const float* __restrict__ Wh1, const float* __restrict__ bh1,
    const float* __restrict__ Wh2, const float* __restrict__ bh2,
    float* __restrict__ out)
{
    const int b = blockIdx.x;
    const int t = threadIdx.x;
    __shared__ float s[128];
    __shared__ float z[44];

    int lo = 0, hi = N;
    while (lo < hi) { int mid = (lo + hi) >> 1; if (batch[mid] < b) lo = mid + 1; else hi = mid; }
    int lo2 = lo, hi2 = N;
    while (lo2 < hi2) { int mid = (lo2 + hi2) >> 1; if (batch[mid] < b + 1) lo2 = mid + 1; else hi2 = mid; }
    const int start = lo, end = lo2;

    const int c = t & 31, r = t >> 5;     // 4 rows x 32 channels in flight
    float acc = 0.f;
    for (int row = start + r; row < end; row += 4)
        acc += bf2f(h[(size_t)row * hstride + c]);
    s[t] = acc;
    __syncthreads();
    if (t < 32) {
        float sum = s[t] + s[t + 32] + s[t + 64] + s[t + 96];
        z[t] = sum / fmaxf((float)(end - start), 1.0f);
    } else if (t < 44) {
        z[t] = meta[(size_t)b * 12 + (t - 32)];
    }
    __syncthreads();
    if (t < 32) {
        float hj = bh1[t];
#pragma unroll
        for (int k = 0; k < 44; ++k)
            hj = fmaf(z[k], Wh1[k * 32 + t], hj);
        hj = fmaxf(hj, 0.f);
        float p = hj * Wh2[t];
#pragma unroll
        for (int off = 16; off >= 1; off >>= 1)
            p += __shfl_xor(p, off, 32);
        if (t == 0) out[b] = p + bh2[0];
    }
}

// =====================================================================
extern "C" void kernel_launch(void* const* d_in, const int* in_sizes, int n_in,
                              void* d_out, int out_size, void* d_ws, size_t ws_size,
                              hipStream_t stream)
{
    const float* x     = (const float*)d_in[0];
    const int*   ei    = (const int*)d_in[1];
    const int*   batch = (const int*)d_in[2];
    const float* meta  = (const float*)d_in[3];
    const float* Wl[3]  = {(const float*)d_in[4],  (const float*)d_in[10], (const float*)d_in[16]};
    const float* bl[3]  = {(const float*)d_in[5],  (const float*)d_in[11], (const float*)d_in[17]};
    const float* Wr[3]  = {(const float*)d_in[6],  (const float*)d_in[12], (const float*)d_in[18]};
    const float* br[3]  = {(const float*)d_in[7],  (const float*)d_in[13], (const float*)d_in[19]};
    const float* att[3] = {(const float*)d_in[8],  (const float*)d_in[14], (const float*)d_in[20]};
    const float* bb[3]  = {(const float*)d_in[9],  (const float*)d_in[15], (const float*)d_in[21]};
    const float* Wh1 = (const float*)d_in[22];
    const float* bh1 = (const float*)d_in[23];
    const float* Wh2 = (const float*)d_in[24];
    const float* bh2 = (const float*)d_in[25];
    float* out = (float*)d_out;

    const int N  = in_sizes[0] / 128;
    const int E  = in_sizes[1] / 2;
    const int B  = in_sizes[3] / 12;
    const int NB = (N + 2047) / 2048;   // scan tiles (<= 256)

    char* wsp = (char*)d_ws;
    size_t off_ = 0;
    auto alloc = [&](size_t bytes) {
        char* p = wsp + off_;
        off_ = (off_ + bytes + 255) & ~(size_t)255;
        return p;
    };
    unsigned short* xlbuf = (unsigned short*)alloc((size_t)N * 128 * 2);  // bf16 gather table
    unsigned short* xrbuf = (unsigned short*)alloc((size_t)N * 128 * 2);  // bf16 xr table
    unsigned short* hbuf  = (unsigned short*)alloc((size_t)N * 128 * 2);  // bf16 layer output
    int*   cnt     = (int*)alloc((size_t)N * 4);
    int*   rowptr  = (int*)alloc((size_t)(N + 1) * 4);
    unsigned short* rank    = (unsigned short*)alloc((size_t)E * 2);  // rank within dst bucket
    unsigned short* csr_src = (unsigned short*)alloc((size_t)E * 2);  // src < 65536
    unsigned short* Bt0     = (unsigned short*)alloc((size_t)256 * 128 * 2);
    unsigned short* Bt1     = (unsigned short*)alloc((size_t)256 * 128 * 2);
    unsigned short* Bt2     = (unsigned short*)alloc((size_t)64 * 128 * 2);
    int*   bsum    = (int*)alloc((size_t)256 * 4);

    const int* srcI = ei;
    const int* dstI = ei + E;

    // ---- weight prep + cnt zeroing (one launch, no memset dispatch)
    prep_w_all<<<(2 * 256 * 128 + 64 * 128 + 255) / 256, 256, 0, stream>>>(
        Wl[0], Wr[0], Wl[1], Wr[1], Wl[2], Wr[2], Bt0, Bt1, Bt2, cnt, N);

    // ---- CSR over dst (real edges; self-loops handled inside gat_fused)
    count_rank_kernel<<<(E + 255) / 256, 256, 0, stream>>>(dstI, E, cnt, rank);
    scan_partial<<<NB, 256, 0, stream>>>(cnt, N, bsum);
    scan_bsums<<<1, 256, 0, stream>>>(bsum, NB, E, rowptr, N);
    scan_final<<<NB, 256, 0, stream>>>(cnt, N, bsum, rowptr);
    place_kernel<<<(E + 255) / 256, 256, 0, stream>>>(srcI, dstI, rank, E, rowptr, csr_src);

    const int GB = (N + 3) / 4;     // gat_fused blocks (4 nodes / 256-thread block)
    const int MB = (N + 63) / 64;   // gemm row-tiles (BM=64)

    // ---- layer 0 (din=128 f32, H=4, C=32, concat)
    {
        gemm_mfma<128, false><<<dim3(MB, 2), 256, 0, stream>>>(x, N, Bt0, bl[0], br[0], 128, xlbuf, xrbuf);
        gat_fused<4><<<GB, 256, 0, stream>>>(xlbuf, xrbuf, rowptr, csr_src, att[0], bb[0], hbuf, 128, N);
    }
    // ---- layer 1 (din=128 bf16)
    {
        gemm_mfma<128, true><<<dim3(MB, 2), 256, 0, stream>>>(hbuf, N, Bt1, bl[1], br[1], 128, xlbuf, xrbuf);
        gat_fused<4><<<GB, 256, 0, stream>>>(xlbuf, xrbuf, rowptr, csr_src, att[1], bb[1], hbuf, 128, N);
    }
    // ---- layer 2 (H=1, concat=False -> mean over 1 head = identity)
    {
        gemm_mfma<64, true><<<dim3(MB, 1), 256, 0, stream>>>(hbuf, N, Bt2, bl[2], br[2], 32, xlbuf, xrbuf);
        gat_fused<1><<<GB, 256, 0, stream>>>(xlbuf, xrbuf, rowptr, csr_src, att[2], bb[2], hbuf, 32, N);
    }
    // ---- fused global mean pool + head (batch sorted -> binary search, no atomics)
    pool_head_kernel<<<B, 128, 0, stream>>>(hbuf, 32, batch, N, meta, Wh1, bh1, Wh2, bh2, out);
}